// Round 16
// baseline (22.798 us; speedup 1.0000x reference)
//
#include <hip/hip_runtime.h>
#include <math.h>

// Problem constants (B=16, H=512, W=512, fp32 in/out)
#define BB 16
#define HH 512
#define WW 512
#define NPIX (BB*HH*WW)   // 4194304
#define NWORDS 16         // 512 rows / 32 bits (full res)
#define HB 256            // half-res grid 256x256
#define HWORDS 8          // 256 block-rows / 32
#define NBLK 1024         // edt_loss blocks = 16 images * 64

// extract even bits 0,2,4,..,30 of x into low 16 bits
__device__ inline unsigned int even16(unsigned int x) {
  x &= 0x55555555u;
  x = (x | (x >> 1)) & 0x33333333u;
  x = (x | (x >> 2)) & 0x0F0F0F0Fu;
  x = (x | (x >> 4)) & 0x00FF00FFu;
  x = (x | (x >> 8)) & 0x0000FFFFu;
  return x;
}

// ---------------------------------------------------------------------------
// Kernel A (R15-proven): full-res column bitmasks + 2x2-downsampled half-res
// bitmask + half-res nearest-set-bit tables. Also zeroes the 33 completion
// counters (visible to kernel B's LLC atomics via the kernel-end release).
// ---------------------------------------------------------------------------
__global__ __launch_bounds__(256) void build_kernel(
    const float* __restrict__ tg, unsigned int* __restrict__ mask,
    unsigned int* __restrict__ hmask, short* __restrict__ un_h,
    short* __restrict__ dn_h, unsigned int* __restrict__ counters) {
  __shared__ unsigned int smask[NWORDS][32];
  __shared__ unsigned int hsm[HWORDS][16];
  int wt = blockIdx.x & 15;          // 16 col-tiles of 32
  int b  = blockIdx.x >> 4;
  int c2 = threadIdx.x & 15;         // 0..15 -> columns {2c2, 2c2+1}
  int k  = threadIdx.x >> 4;         // 0..15
  int w  = (wt << 5) + (c2 << 1);
  if (blockIdx.x == 0 && threadIdx.x < 33) counters[threadIdx.x] = 0u;
  const float* p = tg + ((size_t)(b * HH + (k << 5))) * WW + w;
  unsigned int w0 = 0, w1 = 0;
  #pragma unroll
  for (int r = 0; r < 32; ++r) {
    float2 v = *(const float2*)&p[(size_t)r * WW];
    w0 |= (v.x > 0.f ? 1u : 0u) << r;
    w1 |= (v.y > 0.f ? 1u : 0u) << r;
  }
  smask[k][(c2 << 1)] = w0;
  smask[k][(c2 << 1) + 1] = w1;
  *(uint2*)&mask[(b * NWORDS + k) * WW + w] = make_uint2(w0, w1);
  __syncthreads();
  int t = threadIdx.x;
  if (t < 128) {                     // half-res pack: 8 words x 16 block-cols
    int kp  = t >> 4;                // 0..7
    int bcl = t & 15;                // 0..15
    unsigned int wa = smask[2 * kp][2 * bcl] | smask[2 * kp][2 * bcl + 1];
    unsigned int wb = smask[2 * kp + 1][2 * bcl] | smask[2 * kp + 1][2 * bcl + 1];
    unsigned int hword = even16(wa | (wa >> 1)) | (even16(wb | (wb >> 1)) << 16);
    hsm[kp][bcl] = hword;
    hmask[(b * HWORDS + kp) * HB + (wt << 4) + bcl] = hword;
  }
  __syncthreads();
  if (t < 16) {                      // suffix scan: first set block-row >= 32kp
    int bc = (wt << 4) + t;
    int cur = 16000;
    un_h[(b * 9 + 8) * HB + bc] = (short)cur;
    #pragma unroll
    for (int kp = HWORDS - 1; kp >= 0; --kp) {
      unsigned int m = hsm[kp][t];
      if (m) cur = (kp << 5) + (int)__builtin_ctz(m);
      un_h[(b * 9 + kp) * HB + bc] = (short)cur;
    }
  } else if (t >= 64 && t < 80) {    // prefix scan: last set block-row <= 32kp+31
    int tt = t - 64;
    int bc = (wt << 4) + tt;
    int cur = -16000;
    dn_h[(b * 9 + 0) * HB + bc] = (short)cur;
    #pragma unroll
    for (int kp = 0; kp < HWORDS; ++kp) {
      unsigned int m = hsm[kp][tt];
      if (m) cur = (kp << 5) + 31 - (int)__builtin_clz(m);
      dn_h[(b * 9 + kp + 1) * HB + bc] = (short)cur;
    }
  }
}

// ---------------------------------------------------------------------------
// Kernel B: R15-proven WAVE-PER-ROW half-res EDT + loss, plus:
//  - logits loads hoisted above the horizontal scan (latency hiding);
//  - fused finalize via a TWO-LEVEL contention-free counter:
//      publish 4 partials (agent stores, fixed slots) -> vmcnt(0) ->
//      atomicAdd sub-counter[g&31] (32-deep each, parallel across 32 addrs);
//      32nd of a sub adds to the master; 32nd on master = true last block ->
//      reads all 1024x4 partials (independent agent loads) and reduces in
//      FIXED slot order -> bitwise deterministic scalar. No __threadfence,
//      no grid.sync, no single-address burst (R14's failure mode).
// ---------------------------------------------------------------------------
__global__ __launch_bounds__(256) void edt_loss_kernel(
    const float* __restrict__ logits, const unsigned int* __restrict__ mask,
    const unsigned int* __restrict__ hmask, const short* __restrict__ un_h,
    const short* __restrict__ dn_h, float* __restrict__ partials,
    unsigned int* __restrict__ counters, float* __restrict__ out) {
  __shared__ __align__(16) float srow[4][768];   // [pad 256 | data 256 | pad 256]
  __shared__ float wsum[4][4];
  __shared__ int lastflag;

  int g = blockIdx.x;
  int b = g >> 6, Rbase = (g & 63) << 2;
  int tid = threadIdx.x;
  int wv = tid >> 6, lane = tid & 63;
  int R = Rbase + wv;
  int c0 = lane << 2;                 // this lane's 4 half-res columns
  float* sA = &srow[wv][256];

  // pads: 8 floats/lane (left 4 + right 4), own row only
  *(float4*)&srow[wv][lane << 2] = make_float4(3e12f, 3e12f, 3e12f, 3e12f);
  *(float4*)&srow[wv][512 + (lane << 2)] = make_float4(3e12f, 3e12f, 3e12f, 3e12f);

  // ---- hoisted loss loads (HBM latency hides under the scan) ----
  int wcl = lane << 3;
  size_t lb0 = ((size_t)(b * HH + (R << 1))) * WW + wcl;
  float4 xA0 = *(const float4*)&logits[lb0];
  float4 xB0 = *(const float4*)&logits[lb0 + 4];
  float4 xA1 = *(const float4*)&logits[lb0 + WW];
  float4 xB1 = *(const float4*)&logits[lb0 + WW + 4];

  // ---- vertical EDT: 4 columns, O(1) each from tables ----
  int k0 = R >> 5, pos = R & 31;      // wave-uniform
  unsigned int pmask_lo = (1u << pos) - 1u;
  unsigned int pmask_le = pmask_lo | (1u << pos);
  int kb = k0 << 5;
  uint4 hm = *(const uint4*)&hmask[(b * HWORDS + k0) * HB + c0];
  short4 un4 = *(const short4*)&un_h[(b * 9 + k0 + 1) * HB + c0];
  short4 dn4 = *(const short4*)&dn_h[(b * 9 + k0) * HB + c0];

  float dv0, dv1, dv2, dv3;
#define VERT(MC, UNC, DNC, DVOUT)                                         \
  { unsigned int upm  = (MC) & ~pmask_lo;                                 \
    unsigned int lowm = (MC) & pmask_le;                                  \
    int up  = upm  ? (kb + (int)__builtin_ctz(upm))        : (int)(UNC);  \
    int dnv = lowm ? (kb + 31 - (int)__builtin_clz(lowm))  : (int)(DNC);  \
    int bv = min(up - R, R - dnv);                                        \
    DVOUT = (bv > 255) ? 1e12f : (float)(bv * bv); }
  VERT(hm.x, un4.x, dn4.x, dv0)
  VERT(hm.y, un4.y, dn4.y, dv1)
  VERT(hm.z, un4.z, dn4.z, dv2)
  VERT(hm.w, un4.w, dn4.w, dv3)
#undef VERT
  *(float4*)&sA[c0] = make_float4(dv0, dv1, dv2, dv3);
  __syncthreads();   // all 4 rows staged

  // ---- horizontal min-plus: shared-window scan, 4 px/lane ----
  float b0 = dv0, b1 = dv1, b2 = dv2, b3 = dv3;
  for (int o0 = 1; o0 < HB; o0 += 8) {   // o0 odd -> windows float2-aligned
    float bmax = fmaxf(fmaxf(b0, b1), fmaxf(b2, b3));
    if (__all((float)(o0 * o0) >= bmax)) break;   // own-wave vote only
    const float2* Lp = (const float2*)&sA[c0 - o0 - 7];
    const float2* Rp = (const float2*)&sA[c0 + o0 - 1];
    float2 L0 = Lp[0], L1 = Lp[1], L2 = Lp[2], L3 = Lp[3], L4 = Lp[4], L5 = Lp[5];
    float2 R0 = Rp[0], R1 = Rp[1], R2 = Rp[2], R3 = Rp[3], R4 = Rp[4], R5 = Rp[5];
#define STEP(U, A0, B0, A1, B1, A2, B2, A3, B3)             \
    { float oo = (float)((o0 + (U)) * (o0 + (U)));          \
      b0 = fminf(b0, fminf((A0), (B0)) + oo);               \
      b1 = fminf(b1, fminf((A1), (B1)) + oo);               \
      b2 = fminf(b2, fminf((A2), (B2)) + oo);               \
      b3 = fminf(b3, fminf((A3), (B3)) + oo); }
    STEP(0, L3.y, R0.y, L4.x, R1.x, L4.y, R1.y, L5.x, R2.x)
    STEP(1, L3.x, R1.x, L3.y, R1.y, L4.x, R2.x, L4.y, R2.y)
    STEP(2, L2.y, R1.y, L3.x, R2.x, L3.y, R2.y, L4.x, R3.x)
    STEP(3, L2.x, R2.x, L2.y, R2.y, L3.x, R3.x, L3.y, R3.y)
    STEP(4, L1.y, R2.y, L2.x, R3.x, L2.y, R3.y, L3.x, R4.x)
    STEP(5, L1.x, R3.x, L1.y, R3.y, L2.x, R4.x, L2.y, R4.y)
    STEP(6, L0.y, R3.y, L1.x, R4.x, L1.y, R4.y, L2.x, R5.x)
    STEP(7, L0.x, R4.x, L0.y, R4.y, L1.x, R5.x, L1.y, R5.y)
#undef STEP
  }

  // ---- weights in registers ----
#define WGT(BC) (((BC) > 1e9f) ? 0.f \
                 : (1.f - __expf(-__builtin_amdgcn_sqrtf(BC) * 0.04f)))
  float wg0 = WGT(b0), wg1 = WGT(b1), wg2 = WGT(b2), wg3 = WGT(b3);
#undef WGT

  // ---- loss for full rows {2R, 2R+1}, cols 8*lane..8*lane+7 ----
  float acc_p = 0.f, acc_t = 0.f, acc_pt = 0.f, acc_pen = 0.f;
#define PX(XC, WC, MC, BIT)                                 \
  { float x = (XC);                                         \
    float tt = (float)(((MC) >> (BIT)) & 1u);               \
    float e = __expf(-x);                                   \
    float pp = __builtin_amdgcn_rcpf(1.f + e);              \
    acc_p += pp; acc_t += tt; acc_pt += pp * tt;            \
    acc_pen += (WC) * pp * (1.f - tt); }
#define ROW_LOSS(RR, XA, XB)                                                \
  { int i = (R << 1) + (RR);                                                \
    int bit = i & 31;                                                       \
    const unsigned int* mrow = &mask[(b * NWORDS + (i >> 5)) * WW + wcl];   \
    uint4 mA = *(const uint4*)&mrow[0];                                     \
    uint4 mB = *(const uint4*)&mrow[4];                                     \
    PX(XA.x, wg0, mA.x, bit) PX(XA.y, wg0, mA.y, bit)                       \
    PX(XA.z, wg1, mA.z, bit) PX(XA.w, wg1, mA.w, bit)                       \
    PX(XB.x, wg2, mB.x, bit) PX(XB.y, wg2, mB.y, bit)                       \
    PX(XB.z, wg3, mB.z, bit) PX(XB.w, wg3, mB.w, bit) }
  ROW_LOSS(0, xA0, xB0)
  ROW_LOSS(1, xA1, xB1)
#undef ROW_LOSS
#undef PX

  // ---- block reduce (wave shuffle + cross-wave LDS) ----
  #pragma unroll
  for (int off = 32; off; off >>= 1) {
    acc_p  += __shfl_down(acc_p,  off);
    acc_t  += __shfl_down(acc_t,  off);
    acc_pt += __shfl_down(acc_pt, off);
    acc_pen += __shfl_down(acc_pen, off);
  }
  if (lane == 0) {
    wsum[wv][0] = acc_p; wsum[wv][1] = acc_t;
    wsum[wv][2] = acc_pt; wsum[wv][3] = acc_pen;
  }
  __syncthreads();
  if (tid == 0) {
    float r0 = 0.f, r1 = 0.f, r2 = 0.f, r3 = 0.f;
    #pragma unroll
    for (int q = 0; q < 4; ++q) {
      r0 += wsum[q][0]; r1 += wsum[q][1];
      r2 += wsum[q][2]; r3 += wsum[q][3];
    }
    // publish partials at the coherent point (fixed slots)
    __hip_atomic_store(&partials[0 * NBLK + g], r0, __ATOMIC_RELAXED,
                       __HIP_MEMORY_SCOPE_AGENT);
    __hip_atomic_store(&partials[1 * NBLK + g], r1, __ATOMIC_RELAXED,
                       __HIP_MEMORY_SCOPE_AGENT);
    __hip_atomic_store(&partials[2 * NBLK + g], r2, __ATOMIC_RELAXED,
                       __HIP_MEMORY_SCOPE_AGENT);
    __hip_atomic_store(&partials[3 * NBLK + g], r3, __ATOMIC_RELAXED,
                       __HIP_MEMORY_SCOPE_AGENT);
    asm volatile("s_waitcnt vmcnt(0)" ::: "memory");
    // two-level completion counter: 32 subs (32-deep each) + 1 master
    unsigned int sub = __hip_atomic_fetch_add(&counters[g & 31], 1u,
                                              __ATOMIC_RELAXED,
                                              __HIP_MEMORY_SCOPE_AGENT);
    int last = 0;
    if (sub == 31u) {
      unsigned int mst = __hip_atomic_fetch_add(&counters[32], 1u,
                                                __ATOMIC_RELAXED,
                                                __HIP_MEMORY_SCOPE_AGENT);
      last = (mst == 31u) ? 1 : 0;
    }
    lastflag = last;
  }
  __syncthreads();

  // last finished block: deterministic fixed-order reduce of 1024x4 partials
  if (lastflag) {
    float a0 = 0.f, a1 = 0.f, a2 = 0.f, a3 = 0.f;
    for (int kq = tid; kq < NBLK; kq += 256) {
      a0 += __hip_atomic_load(&partials[0 * NBLK + kq], __ATOMIC_RELAXED,
                              __HIP_MEMORY_SCOPE_AGENT);
      a1 += __hip_atomic_load(&partials[1 * NBLK + kq], __ATOMIC_RELAXED,
                              __HIP_MEMORY_SCOPE_AGENT);
      a2 += __hip_atomic_load(&partials[2 * NBLK + kq], __ATOMIC_RELAXED,
                              __HIP_MEMORY_SCOPE_AGENT);
      a3 += __hip_atomic_load(&partials[3 * NBLK + kq], __ATOMIC_RELAXED,
                              __HIP_MEMORY_SCOPE_AGENT);
    }
    #pragma unroll
    for (int off = 32; off; off >>= 1) {
      a0 += __shfl_down(a0, off);
      a1 += __shfl_down(a1, off);
      a2 += __shfl_down(a2, off);
      a3 += __shfl_down(a3, off);
    }
    if (lane == 0) {
      wsum[wv][0] = a0; wsum[wv][1] = a1;
      wsum[wv][2] = a2; wsum[wv][3] = a3;
    }
    __syncthreads();
    if (tid == 0) {
      float sp = 0.f, st = 0.f, inter = 0.f, pen = 0.f;
      #pragma unroll
      for (int q = 0; q < 4; ++q) {
        sp += wsum[q][0]; st += wsum[q][1];
        inter += wsum[q][2]; pen += wsum[q][3];
      }
      float uni = sp + st - inter;
      float iou_loss = 1.f - (inter + 1e-6f) / (uni + 1e-6f);
      float penalty = pen / (float)NPIX;
      out[0] = iou_loss + 0.5f * penalty;
    }
  }
}

extern "C" void kernel_launch(void* const* d_in, const int* in_sizes, int n_in,
                              void* d_out, int out_size, void* d_ws, size_t ws_size,
                              hipStream_t stream) {
  const float* logits = (const float*)d_in[0];
  const float* tg     = (const float*)d_in[1];
  char* base = (char*)d_ws;
  unsigned int* mask  = (unsigned int*)base;                 // 512 KB
  unsigned int* hmask = (unsigned int*)(base + 524288);      // 128 KB
  short* un_h = (short*)(base + 655360);                     // 72 KB
  short* dn_h = (short*)(base + 729088);                     // 72 KB
  float* partials = (float*)(base + 802816);                 // 16 KB
  unsigned int* counters = (unsigned int*)(base + 819200);   // 33 words
  float* out = (float*)d_out;

  hipLaunchKernelGGL(build_kernel, dim3(256), dim3(256), 0, stream,
                     tg, mask, hmask, un_h, dn_h, counters);
  hipLaunchKernelGGL(edt_loss_kernel, dim3(NBLK), dim3(256), 0, stream,
                     logits, mask, hmask, un_h, dn_h, partials, counters, out);
}

// Round 17
// 19.388 us; speedup vs baseline: 1.1759x; 1.1759x over previous
//
#include <hip/hip_runtime.h>
#include <math.h>

// Problem constants (B=16, H=512, W=512, fp32 in/out)
#define BB 16
#define HH 512
#define WW 512
#define NPIX (BB*HH*WW)   // 4194304
#define NWORDS 16         // 512 rows / 32 bits (full res)
#define HB 256            // half-res grid 256x256
#define HWORDS 8          // 256 block-rows / 32
#define NBLK 1024         // edt_loss blocks = 16 images * 64

// extract even bits 0,2,4,..,30 of x into low 16 bits
__device__ inline unsigned int even16(unsigned int x) {
  x &= 0x55555555u;
  x = (x | (x >> 1)) & 0x33333333u;
  x = (x | (x >> 2)) & 0x0F0F0F0Fu;
  x = (x | (x >> 4)) & 0x00FF00FFu;
  x = (x | (x >> 8)) & 0x0000FFFFu;
  return x;
}

// ---------------------------------------------------------------------------
// Kernel A (R13/R15-proven): full-res column bitmasks + 2x2-downsampled
// half-res bitmask + half-res nearest-set-bit tables. 256 blocks x 256 thr.
//   un_h[b][kp][bc]   = first set block-row >= 32kp    (slot 8 = +16000)
//   dn_h[b][kp+1][bc] = last  set block-row <= 32kp+31 (slot 0 = -16000)
// No atomics, no fences. (4x cross-block-coordination experiments all lost
// to the 3-dispatch skeleton: keep stream-ordered dispatches on MI355X.)
// ---------------------------------------------------------------------------
__global__ __launch_bounds__(256) void build_kernel(
    const float* __restrict__ tg, unsigned int* __restrict__ mask,
    unsigned int* __restrict__ hmask, short* __restrict__ un_h,
    short* __restrict__ dn_h) {
  __shared__ unsigned int smask[NWORDS][32];
  __shared__ unsigned int hsm[HWORDS][16];
  int wt = blockIdx.x & 15;          // 16 col-tiles of 32
  int b  = blockIdx.x >> 4;
  int c2 = threadIdx.x & 15;         // 0..15 -> columns {2c2, 2c2+1}
  int k  = threadIdx.x >> 4;         // 0..15
  int w  = (wt << 5) + (c2 << 1);
  const float* p = tg + ((size_t)(b * HH + (k << 5))) * WW + w;
  unsigned int w0 = 0, w1 = 0;
  #pragma unroll
  for (int r = 0; r < 32; ++r) {
    float2 v = *(const float2*)&p[(size_t)r * WW];
    w0 |= (v.x > 0.f ? 1u : 0u) << r;
    w1 |= (v.y > 0.f ? 1u : 0u) << r;
  }
  smask[k][(c2 << 1)] = w0;
  smask[k][(c2 << 1) + 1] = w1;
  *(uint2*)&mask[(b * NWORDS + k) * WW + w] = make_uint2(w0, w1);
  __syncthreads();
  int t = threadIdx.x;
  if (t < 128) {                     // half-res pack: 8 words x 16 block-cols
    int kp  = t >> 4;                // 0..7
    int bcl = t & 15;                // 0..15
    unsigned int wa = smask[2 * kp][2 * bcl] | smask[2 * kp][2 * bcl + 1];
    unsigned int wb = smask[2 * kp + 1][2 * bcl] | smask[2 * kp + 1][2 * bcl + 1];
    unsigned int hword = even16(wa | (wa >> 1)) | (even16(wb | (wb >> 1)) << 16);
    hsm[kp][bcl] = hword;
    hmask[(b * HWORDS + kp) * HB + (wt << 4) + bcl] = hword;
  }
  __syncthreads();
  if (t < 16) {                      // suffix scan: first set block-row >= 32kp
    int bc = (wt << 4) + t;
    int cur = 16000;
    un_h[(b * 9 + 8) * HB + bc] = (short)cur;
    #pragma unroll
    for (int kp = HWORDS - 1; kp >= 0; --kp) {
      unsigned int m = hsm[kp][t];
      if (m) cur = (kp << 5) + (int)__builtin_ctz(m);
      un_h[(b * 9 + kp) * HB + bc] = (short)cur;
    }
  } else if (t >= 64 && t < 80) {    // prefix scan: last set block-row <= 32kp+31
    int tt = t - 64;
    int bc = (wt << 4) + tt;
    int cur = -16000;
    dn_h[(b * 9 + 0) * HB + bc] = (short)cur;
    #pragma unroll
    for (int kp = 0; kp < HWORDS; ++kp) {
      unsigned int m = hsm[kp][tt];
      if (m) cur = (kp << 5) + 31 - (int)__builtin_clz(m);
      dn_h[(b * 9 + kp + 1) * HB + bc] = (short)cur;
    }
  }
}

// ---------------------------------------------------------------------------
// Kernel B (R15-proven): WAVE-PER-ROW half-res EDT + loss. 1024 blocks x 256
// threads; block (b, Rbase); wave wv owns half-res row R = Rbase+wv:
//   vertical EDT 4 cols/lane -> float4 to own LDS row;
//   horizontal min-plus: shared-window scan, 4 px/lane, 12 named float2
//     window regs per chunk, wave-uniform early exit (own wave only);
//   weights stay in REGISTERS; loss for full rows {2R,2R+1}, 8 px/row/lane.
// Only 2 barriers total. No atomics, no fences, no indexed local arrays.
// ---------------------------------------------------------------------------
__global__ __launch_bounds__(256) void edt_loss_kernel(
    const float* __restrict__ logits, const unsigned int* __restrict__ mask,
    const unsigned int* __restrict__ hmask, const short* __restrict__ un_h,
    const short* __restrict__ dn_h, float* __restrict__ partials) {
  __shared__ __align__(16) float srow[4][768];   // [pad 256 | data 256 | pad 256]
  __shared__ float wsum[4][4];

  int g = blockIdx.x;
  int b = g >> 6, Rbase = (g & 63) << 2;
  int tid = threadIdx.x;
  int wv = tid >> 6, lane = tid & 63;
  int R = Rbase + wv;
  int c0 = lane << 2;                 // this lane's 4 half-res columns
  float* sA = &srow[wv][256];

  // pads: 8 floats/lane (left 4 + right 4), own row only
  *(float4*)&srow[wv][lane << 2] = make_float4(3e12f, 3e12f, 3e12f, 3e12f);
  *(float4*)&srow[wv][512 + (lane << 2)] = make_float4(3e12f, 3e12f, 3e12f, 3e12f);

  // ---- vertical EDT: 4 columns, O(1) each from tables ----
  int k0 = R >> 5, pos = R & 31;      // wave-uniform
  unsigned int pmask_lo = (1u << pos) - 1u;
  unsigned int pmask_le = pmask_lo | (1u << pos);
  int kb = k0 << 5;
  uint4 hm = *(const uint4*)&hmask[(b * HWORDS + k0) * HB + c0];
  short4 un4 = *(const short4*)&un_h[(b * 9 + k0 + 1) * HB + c0];
  short4 dn4 = *(const short4*)&dn_h[(b * 9 + k0) * HB + c0];

  float dv0, dv1, dv2, dv3;
#define VERT(MC, UNC, DNC, DVOUT)                                         \
  { unsigned int upm  = (MC) & ~pmask_lo;                                 \
    unsigned int lowm = (MC) & pmask_le;                                  \
    int up  = upm  ? (kb + (int)__builtin_ctz(upm))        : (int)(UNC);  \
    int dnv = lowm ? (kb + 31 - (int)__builtin_clz(lowm))  : (int)(DNC);  \
    int bv = min(up - R, R - dnv);                                        \
    DVOUT = (bv > 255) ? 1e12f : (float)(bv * bv); }
  VERT(hm.x, un4.x, dn4.x, dv0)
  VERT(hm.y, un4.y, dn4.y, dv1)
  VERT(hm.z, un4.z, dn4.z, dv2)
  VERT(hm.w, un4.w, dn4.w, dv3)
#undef VERT
  *(float4*)&sA[c0] = make_float4(dv0, dv1, dv2, dv3);
  __syncthreads();   // all 4 rows staged (single barrier for the whole EDT)

  // ---- horizontal min-plus: shared-window scan, 4 px/lane ----
  float b0 = dv0, b1 = dv1, b2 = dv2, b3 = dv3;
  for (int o0 = 1; o0 < HB; o0 += 8) {   // o0 odd -> windows float2-aligned
    float bmax = fmaxf(fmaxf(b0, b1), fmaxf(b2, b3));
    if (__all((float)(o0 * o0) >= bmax)) break;   // own-wave vote only
    const float2* Lp = (const float2*)&sA[c0 - o0 - 7];  // idx c0-o0-7 .. +4
    const float2* Rp = (const float2*)&sA[c0 + o0 - 1];  // idx c0+o0-1 .. +10
    float2 L0 = Lp[0], L1 = Lp[1], L2 = Lp[2], L3 = Lp[3], L4 = Lp[4], L5 = Lp[5];
    float2 R0 = Rp[0], R1 = Rp[1], R2 = Rp[2], R3 = Rp[3], R4 = Rp[4], R5 = Rp[5];
    // px_k (k=0..3): left idx offset (7+k)-u, right idx offset (u+1+k)
#define STEP(U, A0, B0, A1, B1, A2, B2, A3, B3)             \
    { float oo = (float)((o0 + (U)) * (o0 + (U)));          \
      b0 = fminf(b0, fminf((A0), (B0)) + oo);               \
      b1 = fminf(b1, fminf((A1), (B1)) + oo);               \
      b2 = fminf(b2, fminf((A2), (B2)) + oo);               \
      b3 = fminf(b3, fminf((A3), (B3)) + oo); }
    STEP(0, L3.y, R0.y, L4.x, R1.x, L4.y, R1.y, L5.x, R2.x)
    STEP(1, L3.x, R1.x, L3.y, R1.y, L4.x, R2.x, L4.y, R2.y)
    STEP(2, L2.y, R1.y, L3.x, R2.x, L3.y, R2.y, L4.x, R3.x)
    STEP(3, L2.x, R2.x, L2.y, R2.y, L3.x, R3.x, L3.y, R3.y)
    STEP(4, L1.y, R2.y, L2.x, R3.x, L2.y, R3.y, L3.x, R4.x)
    STEP(5, L1.x, R3.x, L1.y, R3.y, L2.x, R4.x, L2.y, R4.y)
    STEP(6, L0.y, R3.y, L1.x, R4.x, L1.y, R4.y, L2.x, R5.x)
    STEP(7, L0.x, R4.x, L0.y, R4.y, L1.x, R5.x, L1.y, R5.y)
#undef STEP
  }

  // ---- weights in registers (half cols c0..c0+3) ----
#define WGT(BC) (((BC) > 1e9f) ? 0.f \
                 : (1.f - __expf(-__builtin_amdgcn_sqrtf(BC) * 0.04f)))
  float wg0 = WGT(b0), wg1 = WGT(b1), wg2 = WGT(b2), wg3 = WGT(b3);
#undef WGT

  // ---- loss for full rows {2R, 2R+1}, cols 8*lane..8*lane+7 ----
  float acc_p = 0.f, acc_t = 0.f, acc_pt = 0.f, acc_pen = 0.f;
  int wcl = lane << 3;
#define PX(XC, WC, MC, BIT)                                 \
  { float x = (XC);                                         \
    float tt = (float)(((MC) >> (BIT)) & 1u);               \
    float e = __expf(-x);                                   \
    float pp = __builtin_amdgcn_rcpf(1.f + e);              \
    acc_p += pp; acc_t += tt; acc_pt += pp * tt;            \
    acc_pen += (WC) * pp * (1.f - tt); }
#define ROW_LOSS(RR)                                                        \
  { int i = (R << 1) + (RR);                                                \
    int bit = i & 31;                                                       \
    size_t lb = ((size_t)(b * HH + i)) * WW + wcl;                          \
    const unsigned int* mrow = &mask[(b * NWORDS + (i >> 5)) * WW + wcl];   \
    float4 xA = *(const float4*)&logits[lb];                                \
    float4 xB = *(const float4*)&logits[lb + 4];                            \
    uint4 mA = *(const uint4*)&mrow[0];                                     \
    uint4 mB = *(const uint4*)&mrow[4];                                     \
    PX(xA.x, wg0, mA.x, bit) PX(xA.y, wg0, mA.y, bit)                       \
    PX(xA.z, wg1, mA.z, bit) PX(xA.w, wg1, mA.w, bit)                       \
    PX(xB.x, wg2, mB.x, bit) PX(xB.y, wg2, mB.y, bit)                       \
    PX(xB.z, wg3, mB.z, bit) PX(xB.w, wg3, mB.w, bit) }
  ROW_LOSS(0)
  ROW_LOSS(1)
#undef ROW_LOSS
#undef PX

  // ---- block reduce (wave shuffle + cross-wave LDS) ----
  #pragma unroll
  for (int off = 32; off; off >>= 1) {
    acc_p  += __shfl_down(acc_p,  off);
    acc_t  += __shfl_down(acc_t,  off);
    acc_pt += __shfl_down(acc_pt, off);
    acc_pen += __shfl_down(acc_pen, off);
  }
  if (lane == 0) {
    wsum[wv][0] = acc_p; wsum[wv][1] = acc_t;
    wsum[wv][2] = acc_pt; wsum[wv][3] = acc_pen;
  }
  __syncthreads();
  if (tid == 0) {
    float r0 = 0.f, r1 = 0.f, r2 = 0.f, r3 = 0.f;
    #pragma unroll
    for (int q = 0; q < 4; ++q) {
      r0 += wsum[q][0]; r1 += wsum[q][1];
      r2 += wsum[q][2]; r3 += wsum[q][3];
    }
    partials[0 * NBLK + g] = r0;
    partials[1 * NBLK + g] = r1;
    partials[2 * NBLK + g] = r2;
    partials[3 * NBLK + g] = r3;
  }
}

// ---------------------------------------------------------------------------
// Kernel C: deterministic final reduce of 1024x4 partials + scalar loss.
// ---------------------------------------------------------------------------
__global__ __launch_bounds__(256) void finalize_kernel(
    const float* __restrict__ partials, float* __restrict__ out) {
  __shared__ float wsum[4][4];
  int tid = threadIdx.x;
  float a0 = 0.f, a1 = 0.f, a2 = 0.f, a3 = 0.f;
  for (int k = tid; k < NBLK; k += 256) {
    a0 += partials[0 * NBLK + k];
    a1 += partials[1 * NBLK + k];
    a2 += partials[2 * NBLK + k];
    a3 += partials[3 * NBLK + k];
  }
  #pragma unroll
  for (int off = 32; off; off >>= 1) {
    a0 += __shfl_down(a0, off);
    a1 += __shfl_down(a1, off);
    a2 += __shfl_down(a2, off);
    a3 += __shfl_down(a3, off);
  }
  int wave = tid >> 6, lane = tid & 63;
  if (lane == 0) {
    wsum[wave][0] = a0; wsum[wave][1] = a1;
    wsum[wave][2] = a2; wsum[wave][3] = a3;
  }
  __syncthreads();
  if (tid == 0) {
    float sp = 0.f, st = 0.f, inter = 0.f, pen = 0.f;
    #pragma unroll
    for (int wv = 0; wv < 4; ++wv) {
      sp += wsum[wv][0]; st += wsum[wv][1];
      inter += wsum[wv][2]; pen += wsum[wv][3];
    }
    float uni = sp + st - inter;
    float iou_loss = 1.f - (inter + 1e-6f) / (uni + 1e-6f);
    float penalty = pen / (float)NPIX;
    out[0] = iou_loss + 0.5f * penalty;
  }
}

extern "C" void kernel_launch(void* const* d_in, const int* in_sizes, int n_in,
                              void* d_out, int out_size, void* d_ws, size_t ws_size,
                              hipStream_t stream) {
  const float* logits = (const float*)d_in[0];
  const float* tg     = (const float*)d_in[1];
  char* base = (char*)d_ws;
  unsigned int* mask  = (unsigned int*)base;                 // 512 KB
  unsigned int* hmask = (unsigned int*)(base + 524288);      // 128 KB
  short* un_h = (short*)(base + 655360);                     // 72 KB
  short* dn_h = (short*)(base + 729088);                     // 72 KB
  float* partials = (float*)(base + 802816);                 // 16 KB
  float* out = (float*)d_out;

  hipLaunchKernelGGL(build_kernel, dim3(256), dim3(256), 0, stream,
                     tg, mask, hmask, un_h, dn_h);
  hipLaunchKernelGGL(edt_loss_kernel, dim3(NBLK), dim3(256), 0, stream,
                     logits, mask, hmask, un_h, dn_h, partials);
  hipLaunchKernelGGL(finalize_kernel, dim3(1), dim3(256), 0, stream,
                     partials, out);
}